// Round 3
// baseline (6216.534 us; speedup 1.0000x reference)
//
#include <hip/hip_runtime.h>

typedef unsigned short u16;
typedef unsigned int u32;
typedef __attribute__((ext_vector_type(4))) float f32x4;
typedef __attribute__((ext_vector_type(4))) u16 u16x4;
typedef __attribute__((ext_vector_type(8))) __bf16 bf16x8;

#define TSTEPS 50
#define BB 256
#define II 1024
#define HH 4096
#define LL 10
#define NPLANE ((size_t)BB*HH)

__device__ __forceinline__ u16 f2bf(float f){
  u32 u = __float_as_uint(f);
  u += 0x7fffu + ((u >> 16) & 1u);
  return (u16)(u >> 16);
}
__device__ __forceinline__ float bf2f(u16 u){ return __uint_as_float(((u32)u) << 16); }

__device__ __forceinline__ void async_cp16(const void* g, void* l){
  auto gp = (const __attribute__((address_space(1))) void*)(unsigned long long)(g);
  auto lp = (__attribute__((address_space(3))) void*)(unsigned int)(unsigned long long)(l);
  __builtin_amdgcn_global_load_lds(gp, lp, 16, 0, 0);
}

// ---------------- forward: split-K over 5 planes of K=1024 ------------------
// plane 0: x_t @ w_in^T ; planes 1..4: z_old @ w_rec^T (k-chunks of 1024)
// tile: 64(batch) x 128(H), BK=64, double-buffered (T3-minimal 2-phase).
// grid: 640 flat, XCD-chunk swizzled (640 = 8*80).
__global__ void __launch_bounds__(256) gemm_fwd(
    const u16* __restrict__ xbt, const u16* __restrict__ wib,
    const u16* __restrict__ zb,  const u16* __restrict__ wrb,
    float* __restrict__ pbuf)
{
  __shared__ u16 lsA[2][64*64];    // 8KB per buf
  __shared__ u16 lsB[2][128*64];   // 16KB per buf
  const int tid = threadIdx.x, lane = tid & 63, wid = tid >> 6;
  const int wm = wid & 1, wn = wid >> 1;

  int bid = blockIdx.x;
  int oid = (bid & 7)*80 + (bid >> 3);     // bijective: 640 = 8*80
  int z   = oid >> 7;                      // 128 tiles per plane (32n * 4m)
  int rem = oid & 127;
  int n0  = (rem >> 2) * 128;              // H tile
  int m0  = (rem & 3) * 64;                // batch tile

  const u16* __restrict__ Ab; const u16* __restrict__ Bb;
  int lda, ldb, kbase;
  if (z == 0){ Ab = xbt; lda = II; Bb = wib; ldb = II; kbase = 0; }
  else       { Ab = zb;  lda = HH; Bb = wrb; ldb = HH; kbase = (z-1)*1024; }
  float* __restrict__ C = pbuf + (size_t)z*NPLANE;

  auto STAGE = [&](int buf, int k0){
    int kg = kbase + k0;
#pragma unroll
    for (int c = 0; c < 2; ++c){
      int q = c*4 + wid;
      int o = q*1024 + lane*16;
      int row = o >> 7;
      int cb = (o & 127) ^ ((row & 7) << 4);
      async_cp16(Ab + (size_t)(m0 + row)*lda + kg + (cb >> 1), (char*)lsA[buf] + q*1024);
    }
#pragma unroll
    for (int c = 0; c < 4; ++c){
      int q = c*4 + wid;
      int o = q*1024 + lane*16;
      int row = o >> 7;
      int cb = (o & 127) ^ ((row & 7) << 4);
      async_cp16(Bb + (size_t)(n0 + row)*ldb + kg + (cb >> 1), (char*)lsB[buf] + q*1024);
    }
  };

  f32x4 acc[2][4];
#pragma unroll
  for (int a=0;a<2;++a)
#pragma unroll
    for (int b=0;b<4;++b) acc[a][b] = f32x4{0.f,0.f,0.f,0.f};

  STAGE(0, 0);
  __syncthreads();                          // drains vmcnt(0) + barrier
  for (int kt = 0; kt < 16; ++kt){
    int cur = kt & 1;
    if (kt < 15) STAGE(cur ^ 1, (kt+1)*64); // loads fly under the MFMAs
#pragma unroll
    for (int kk = 0; kk < 2; ++kk){
      bf16x8 af[2], bfr[4];
      int kb = kk*64 + ((lane >> 4) << 4);
#pragma unroll
      for (int fm=0; fm<2; ++fm){
        int r = wm*32 + fm*16 + (lane & 15);
        af[fm] = *(const bf16x8*)((const char*)lsA[cur] + r*128 + (kb ^ ((r & 7) << 4)));
      }
#pragma unroll
      for (int fn=0; fn<4; ++fn){
        int r = wn*64 + fn*16 + (lane & 15);
        bfr[fn] = *(const bf16x8*)((const char*)lsB[cur] + r*128 + (kb ^ ((r & 7) << 4)));
      }
#pragma unroll
      for (int fm=0; fm<2; ++fm)
#pragma unroll
        for (int fn=0; fn<4; ++fn)
          acc[fm][fn] = __builtin_amdgcn_mfma_f32_16x16x32_bf16(af[fm], bfr[fn], acc[fm][fn], 0, 0, 0);
    }
    __syncthreads();                        // waits this iter's stage loads
  }

#pragma unroll
  for (int fm=0; fm<2; ++fm)
#pragma unroll
    for (int fn=0; fn<4; ++fn)
#pragma unroll
      for (int r=0; r<4; ++r){
        int row = m0 + wm*32 + fm*16 + ((lane >> 4) << 2) + r;
        int col = n0 + wn*64 + fn*16 + (lane & 15);
        C[(size_t)row*HH + col] = acc[fm][fn][r];
      }
}

// ---------------- merged weight-update GEMM (w_rec tiles + w_in tiles) ------
// C[M,N] += A1[m,k]B1[n,k] + A2[m,k]B2[n,k], K=256 each, f32 RMW + bf16 shadow.
// tile 128x128, BK=64, dbuf. grid 1280 flat (8*160), XCD swizzled.
__global__ void __launch_bounds__(256) gemm_upd(
    const u16* __restrict__ zTw, const u16* __restrict__ tprT,
    const u16* __restrict__ tqrT, const u16* __restrict__ zTr,
    float* __restrict__ o_wrec, u16* __restrict__ wrb,
    const u16* __restrict__ tpiT, const u16* __restrict__ tqiT,
    const u16* __restrict__ xbT,
    float* __restrict__ o_win, u16* __restrict__ wib)
{
  __shared__ u16 lsA[2][128*64];   // 16KB per buf
  __shared__ u16 lsB[2][128*64];
  const int tid = threadIdx.x, lane = tid & 63, wid = tid >> 6;
  const int wm = wid & 1, wn = wid >> 1;

  int bid = blockIdx.x;
  int oid = (bid & 7)*160 + (bid >> 3);    // bijective: 1280 = 8*160
  const u16 *A1, *B1, *A2, *B2; float* C; u16* Cb; int ldc, m0, n0;
  if (oid < 1024){                          // w_rec: 32m x 32n
    m0 = (oid & 31)*128; n0 = (oid >> 5)*128;
    A1 = zTw; B1 = tprT; A2 = tqrT; B2 = zTr; C = o_wrec; Cb = wrb; ldc = HH;
  } else {                                  // w_in: 32m x 8n
    int r = oid - 1024;
    m0 = (r & 31)*128; n0 = (r >> 5)*128;
    A1 = zTw; B1 = tpiT; A2 = tqiT; B2 = xbT; C = o_win; Cb = wib; ldc = II;
  }

  auto STAGE = [&](int buf, int kt){
    const u16* __restrict__ A = (kt < 4) ? A1 : A2;
    const u16* __restrict__ Bm = (kt < 4) ? B1 : B2;
    int k0 = (kt & 3)*64;
#pragma unroll
    for (int c = 0; c < 4; ++c){
      int q = c*4 + wid;
      int o = q*1024 + lane*16;
      int row = o >> 7;
      int cb = (o & 127) ^ ((row & 7) << 4);
      async_cp16(A  + (size_t)(m0 + row)*BB + k0 + (cb >> 1), (char*)lsA[buf] + q*1024);
      async_cp16(Bm + (size_t)(n0 + row)*BB + k0 + (cb >> 1), (char*)lsB[buf] + q*1024);
    }
  };

  f32x4 acc[4][4];
#pragma unroll
  for (int a=0;a<4;++a)
#pragma unroll
    for (int b=0;b<4;++b) acc[a][b] = f32x4{0.f,0.f,0.f,0.f};

  STAGE(0, 0);
  __syncthreads();
  for (int kt = 0; kt < 8; ++kt){
    int cur = kt & 1;
    if (kt < 7) STAGE(cur ^ 1, kt+1);
#pragma unroll
    for (int kk = 0; kk < 2; ++kk){
      bf16x8 af[4], bfr[4];
      int kb = kk*64 + ((lane >> 4) << 4);
#pragma unroll
      for (int f=0; f<4; ++f){
        int ra = wm*64 + f*16 + (lane & 15);
        af[f] = *(const bf16x8*)((const char*)lsA[cur] + ra*128 + (kb ^ ((ra & 7) << 4)));
        int rb = wn*64 + f*16 + (lane & 15);
        bfr[f] = *(const bf16x8*)((const char*)lsB[cur] + rb*128 + (kb ^ ((rb & 7) << 4)));
      }
#pragma unroll
      for (int fm=0; fm<4; ++fm)
#pragma unroll
        for (int fn=0; fn<4; ++fn)
          acc[fm][fn] = __builtin_amdgcn_mfma_f32_16x16x32_bf16(af[fm], bfr[fn], acc[fm][fn], 0, 0, 0);
    }
    __syncthreads();
  }

#pragma unroll
  for (int fm=0; fm<4; ++fm)
#pragma unroll
    for (int fn=0; fn<4; ++fn)
#pragma unroll
      for (int r=0; r<4; ++r){
        int row = m0 + wm*64 + fm*16 + ((lane >> 4) << 2) + r;
        int col = n0 + wn*64 + fn*16 + (lane & 15);
        size_t idx = (size_t)row*ldc + col;
        float nw = C[idx] + acc[fm][fn][r];
        C[idx] = nw;
        Cb[idx] = f2bf(nw);
      }
}

// ---------------- merged per-step elementwise + transposes ------------------
// bid<1024: state tile 64h x 16b ; bid>=1024: tpi tile 64i x 16b
__global__ void __launch_bounds__(256) step_all(
    const float* __restrict__ pbuf,
    float* __restrict__ v, float* __restrict__ iS, float* __restrict__ sc,
    float* __restrict__ tqi, float* __restrict__ tpr, float* __restrict__ tqr,
    const u16* __restrict__ zb_old,
    u16* __restrict__ zb_new, u16* __restrict__ zT_new,
    u16* __restrict__ tqiT, u16* __restrict__ tprT, u16* __restrict__ tqrT,
    const u16* __restrict__ xbt, float* __restrict__ tpi,
    u16* __restrict__ tpiT, u16* __restrict__ xbT)
{
  __shared__ u16 ls[4][64*17];
  const int tid = threadIdx.x;
  const int bid = blockIdx.x;

  if (bid < 1024){
    const int h0 = (bid & 63) * 64;
    const int b0 = (bid >> 6) * 16;
    u16 vz[4], vq[4], vp[4], vr[4];
#pragma unroll
    for (int e=0;e<4;++e){
      int f = e*256 + tid;
      int hl = f & 63, bl = f >> 6;
      size_t idx = (size_t)(b0+bl)*HH + h0 + hl;
      float ic = pbuf[idx] + pbuf[idx + NPLANE] + pbuf[idx + 2*NPLANE]
               + pbuf[idx + 3*NPLANE] + pbuf[idx + 4*NPLANE];
      float vv = v[idx], ii = iS[idx];
      float vdec = vv + 0.05f*((0.0f - vv) + ii);
      float idec = ii - 0.1f*ii;
      float z = (vdec >= 0.5f) ? 1.0f : 0.0f;
      v[idx] = (vdec >= 0.5f) ? 0.0f : vdec;
      iS[idx] = idec + ic;
      float zold = bf2f(zb_old[idx]);
      float q = tqi[idx]; q += 0.0005f*(0.001f*z - q);    tqi[idx] = q;
      float pp = tpr[idx]; pp += 0.0005f*(0.001f*zold - pp); tpr[idx] = pp;
      float rr = tqr[idx]; rr += 0.0005f*(0.001f*z - rr); tqr[idx] = rr;
      sc[idx] += z;
      u16 zb16 = f2bf(z);
      zb_new[idx] = zb16;
      vz[e] = zb16;
      vq[e] = f2bf(-1e-4f * q);   // fold -ETA_MINUS
      vp[e] = f2bf(0.01f * pp);   // fold +ETA_PLUS
      vr[e] = f2bf(-1e-4f * rr);  // fold -ETA_MINUS
    }
#pragma unroll
    for (int e=0;e<4;++e){
      int f=e*256+tid; int hl=f&63, bl=f>>6; int o = hl*17+bl;
      ls[0][o]=vz[e]; ls[1][o]=vq[e]; ls[2][o]=vp[e]; ls[3][o]=vr[e];
    }
    __syncthreads();
#pragma unroll
    for (int e=0;e<4;++e){
      int f=e*256+tid; int bl=f&15, hl=f>>4; int o=hl*17+bl;
      size_t oi = (size_t)(h0+hl)*BB + b0 + bl;
      zT_new[oi]=ls[0][o]; tqiT[oi]=ls[1][o]; tprT[oi]=ls[2][o]; tqrT[oi]=ls[3][o];
    }
  } else {
    const int r0 = bid - 1024;
    const int i0 = (r0 & 15) * 64;
    const int b0 = (r0 >> 4) * 16;
    u16 vp[4], vx[4];
#pragma unroll
    for (int e=0;e<4;++e){
      int f = e*256 + tid;
      int il = f & 63, bl = f >> 6;
      size_t idx = (size_t)(b0+bl)*II + i0 + il;
      u16 xu = xbt[idx];
      float pre = bf2f(xu);
      float p = tpi[idx]; p += 0.0005f*(0.001f*pre - p); tpi[idx] = p;
      vp[e] = f2bf(0.01f*p);  // fold +ETA_PLUS
      vx[e] = xu;
    }
#pragma unroll
    for (int e=0;e<4;++e){
      int f=e*256+tid; int il=f&63, bl=f>>6; int o = il*17+bl;
      ls[0][o]=vp[e]; ls[1][o]=vx[e];
    }
    __syncthreads();
#pragma unroll
    for (int e=0;e<4;++e){
      int f=e*256+tid; int bl=f&15, il=f>>4; int o=il*17+bl;
      size_t oi = (size_t)(i0+il)*BB + b0 + bl;
      tpiT[oi]=ls[0][o]; xbT[oi]=ls[1][o];
    }
  }
}

// ---------------- casts and finalize ---------------------------------------
__global__ void __launch_bounds__(256) cast_x(const f32x4* __restrict__ x, u16x4* __restrict__ xb, long long n4){
  long long i = (long long)blockIdx.x*blockDim.x + threadIdx.x;
  long long stride = (long long)gridDim.x*blockDim.x;
  for (; i < n4; i += stride){
    f32x4 vv = x[i];
    u16x4 o;
#pragma unroll
    for (int j=0;j<4;++j) o[j] = f2bf(vv[j]);
    xb[i] = o;
  }
}

__global__ void __launch_bounds__(256) cast_w(const f32x4* __restrict__ w0, f32x4* __restrict__ wf,
                                              u16x4* __restrict__ wb, long long n4){
  long long i = (long long)blockIdx.x*blockDim.x + threadIdx.x;
  long long stride = (long long)gridDim.x*blockDim.x;
  for (; i < n4; i += stride){
    f32x4 vv = w0[i];
    wf[i] = vv;
    u16x4 o;
#pragma unroll
    for (int j=0;j<4;++j) o[j] = f2bf(vv[j]);
    wb[i] = o;
  }
}

__global__ void __launch_bounds__(256) fin_logits(const float* __restrict__ sc,
                                                  float* __restrict__ logits, float* __restrict__ total){
  __shared__ float bins[LL];
  const int tid = threadIdx.x;
  const int b = blockIdx.x;
  if (tid < LL) bins[tid] = 0.f;
  __syncthreads();
#pragma unroll
  for (int e=0;e<16;++e){
    int h = e*256 + tid;
    float vv = sc[(size_t)b*HH + h];
    int a = h/409; if (a > 9) a = 9;
    atomicAdd(&bins[a], vv);
  }
  __syncthreads();
  if (tid < LL){
    float cnt = (tid==9) ? 415.f : 409.f;
    logits[b*LL + tid] = bins[tid] / (50.f * cnt);
  }
  if (tid == 0){
    float s = 0.f;
    for (int l=0;l<LL;++l) s += bins[l];
    atomicAdd(total, s);
  }
}

// grid (16, 8): 256 h per block-x, 32 batches per block-y; register bins.
__global__ void __launch_bounds__(256) fin_spikecnt(const float* __restrict__ sc,
                                                    const int* __restrict__ label, float* __restrict__ out){
  int h = blockIdx.x*256 + threadIdx.x;
  int bs = blockIdx.y*32;
  float acc[LL];
#pragma unroll
  for (int j=0;j<LL;++j) acc[j] = 0.f;
  for (int b=bs; b<bs+32; ++b){
    int l = label[b];
    float vv = sc[(size_t)b*HH + h];
#pragma unroll
    for (int j=0;j<LL;++j) acc[j] += (j==l) ? vv : 0.f;
  }
#pragma unroll
  for (int j=0;j<LL;++j)
    if (acc[j] != 0.f) atomicAdd(&out[(size_t)j*HH + h], acc[j]);
}

__global__ void __launch_bounds__(256) fin_labelcnt(const int* __restrict__ label, float* __restrict__ out){
  __shared__ int bins[LL];
  const int tid = threadIdx.x;
  if (tid < LL) bins[tid] = 0;
  __syncthreads();
  atomicAdd(&bins[label[tid]], 1);
  __syncthreads();
  if (tid < LL) out[tid] = 50.f * (float)bins[tid];
}

extern "C" void kernel_launch(void* const* d_in, const int* in_sizes, int n_in,
                              void* d_out, int out_size, void* d_ws, size_t ws_size,
                              hipStream_t stream)
{
  (void)in_sizes; (void)n_in; (void)out_size; (void)ws_size;
  const float* x      = (const float*)d_in[0];
  const int*   label  = (const int*)d_in[1];
  const float* w_in0  = (const float*)d_in[2];
  const float* w_rec0 = (const float*)d_in[3];

  float* out      = (float*)d_out;
  float* o_logits = out;                            // 2560
  float* o_total  = out + 2560;                     // 1
  float* o_win    = out + 2561;                     // H*I f32 master (lives in d_out)
  float* o_wrec   = o_win + (size_t)HH*II;          // H*H
  float* o_sc     = o_wrec + (size_t)HH*HH;         // L*H
  float* o_lc     = o_sc + (size_t)LL*HH;           // L

  char* cur = (char*)d_ws;
  auto alloc = [&](size_t bytes)->char*{ char* p = cur; cur += (bytes + 255) & ~(size_t)255; return p; };
  u16*   xb   = (u16*)  alloc((size_t)TSTEPS*BB*II*2);
  u16*   wib  = (u16*)  alloc((size_t)HH*II*2);
  u16*   wrb  = (u16*)  alloc((size_t)HH*HH*2);
  float* v    = (float*)alloc((size_t)BB*HH*4);
  float* iS   = (float*)alloc((size_t)BB*HH*4);
  float* sc   = (float*)alloc((size_t)BB*HH*4);
  float* tpi  = (float*)alloc((size_t)BB*II*4);
  float* tqi  = (float*)alloc((size_t)BB*HH*4);
  float* tpr  = (float*)alloc((size_t)BB*HH*4);
  float* tqr  = (float*)alloc((size_t)BB*HH*4);
  float* pbuf = (float*)alloc((size_t)5*BB*HH*4);
  u16*   zb0  = (u16*)  alloc((size_t)BB*HH*2);
  u16*   zb1  = (u16*)  alloc((size_t)BB*HH*2);
  u16*   zT0  = (u16*)  alloc((size_t)HH*BB*2);
  u16*   zT1  = (u16*)  alloc((size_t)HH*BB*2);
  u16*   tpiT = (u16*)  alloc((size_t)II*BB*2);
  u16*   xbT  = (u16*)  alloc((size_t)II*BB*2);
  u16*   tqiT = (u16*)  alloc((size_t)HH*BB*2);
  u16*   tprT = (u16*)  alloc((size_t)HH*BB*2);
  u16*   tqrT = (u16*)  alloc((size_t)HH*BB*2);
  u16* zb[2] = {zb0, zb1};
  u16* zT[2] = {zT0, zT1};

  hipMemsetAsync(v,    0, (size_t)BB*HH*4, stream);
  hipMemsetAsync(iS,   0, (size_t)BB*HH*4, stream);
  hipMemsetAsync(sc,   0, (size_t)BB*HH*4, stream);
  hipMemsetAsync(tpi,  0, (size_t)BB*II*4, stream);
  hipMemsetAsync(tqi,  0, (size_t)BB*HH*4, stream);
  hipMemsetAsync(tpr,  0, (size_t)BB*HH*4, stream);
  hipMemsetAsync(tqr,  0, (size_t)BB*HH*4, stream);
  hipMemsetAsync(zb0,  0, (size_t)BB*HH*2, stream);
  hipMemsetAsync(zb1,  0, (size_t)BB*HH*2, stream);
  hipMemsetAsync(zT0,  0, (size_t)HH*BB*2, stream);
  hipMemsetAsync(zT1,  0, (size_t)HH*BB*2, stream);
  hipMemsetAsync(o_total, 0, 4, stream);
  hipMemsetAsync(o_sc, 0, (size_t)LL*HH*4, stream);

  cast_w<<<1024, 256, 0, stream>>>((const f32x4*)w_in0,  (f32x4*)o_win,  (u16x4*)wib, (long long)HH*II/4);
  cast_w<<<2048, 256, 0, stream>>>((const f32x4*)w_rec0, (f32x4*)o_wrec, (u16x4*)wrb, (long long)HH*HH/4);
  cast_x<<<2048, 256, 0, stream>>>((const f32x4*)x, (u16x4*)xb, (long long)TSTEPS*BB*II/4);

  for (int t = 0; t < TSTEPS; ++t){
    int wi = t & 1, ri = wi ^ 1;
    const u16* xbt = xb + (size_t)t*BB*II;

    gemm_fwd<<<640, 256, 0, stream>>>(xbt, wib, zb[ri], wrb, pbuf);

    step_all<<<1280, 256, 0, stream>>>(
        pbuf, v, iS, sc, tqi, tpr, tqr,
        zb[ri], zb[wi], zT[wi], tqiT, tprT, tqrT,
        xbt, tpi, tpiT, xbT);

    gemm_upd<<<1280, 256, 0, stream>>>(
        zT[wi], tprT, tqrT, zT[ri], o_wrec, wrb,
        tpiT, tqiT, xbT, o_win, wib);
  }

  fin_logits  <<<BB, 256, 0, stream>>>(sc, o_logits, o_total);
  fin_spikecnt<<<dim3(HH/256, 8), 256, 0, stream>>>(sc, label, o_sc);
  fin_labelcnt<<<1, 256, 0, stream>>>(label, o_lc);
}

// Round 5
// 3194.279 us; speedup vs baseline: 1.9461x; 1.9461x over previous
//
#include <hip/hip_runtime.h>

typedef unsigned short u16;
typedef unsigned int u32;
typedef __attribute__((ext_vector_type(4))) float f32x4;
typedef __attribute__((ext_vector_type(4))) u16 u16x4;
typedef __attribute__((ext_vector_type(8))) __bf16 bf16x8;

#define TSTEPS 50
#define BB 256
#define II 1024
#define HH 4096
#define LL 10
#define NPLANE ((size_t)BB*HH)
#define HB ((size_t)HH*BB)
#define IB ((size_t)II*BB)
#define TC 5          // chunk length
#define NSLOT 6       // ring slots (TC+1)

__device__ __forceinline__ u16 f2bf(float f){
  u32 u = __float_as_uint(f);
  u += 0x7fffu + ((u >> 16) & 1u);
  return (u16)(u >> 16);
}
__device__ __forceinline__ float bf2f(u16 u){ return __uint_as_float(((u32)u) << 16); }

__device__ __forceinline__ void async_cp16(const void* g, void* l){
  auto gp = (const __attribute__((address_space(1))) void*)(unsigned long long)(g);
  auto lp = (__attribute__((address_space(3))) void*)(unsigned int)(unsigned long long)(l);
  __builtin_amdgcn_global_load_lds(gp, lp, 16, 0, 0);
}

// ---------------- forward: split-K over 5 planes of K=1024 ------------------
// plane 0: x_t @ w_in0^T ; planes 1..4: z_old @ w_rec0^T (frozen bf16 weights)
__global__ void __launch_bounds__(256) gemm_fwd(
    const u16* __restrict__ xbt, const u16* __restrict__ wib,
    const u16* __restrict__ zb,  const u16* __restrict__ wrb,
    float* __restrict__ pbuf)
{
  __shared__ u16 lsA[2][64*64];
  __shared__ u16 lsB[2][128*64];
  const int tid = threadIdx.x, lane = tid & 63, wid = tid >> 6;
  const int wm = wid & 1, wn = wid >> 1;

  int bid = blockIdx.x;
  int oid = (bid & 7)*80 + (bid >> 3);     // bijective: 640 = 8*80
  int z   = oid >> 7;
  int rem = oid & 127;
  int n0  = (rem >> 2) * 128;
  int m0  = (rem & 3) * 64;

  const u16* __restrict__ Ab; const u16* __restrict__ Bb;
  int lda, ldb, kbase;
  if (z == 0){ Ab = xbt; lda = II; Bb = wib; ldb = II; kbase = 0; }
  else       { Ab = zb;  lda = HH; Bb = wrb; ldb = HH; kbase = (z-1)*1024; }
  float* __restrict__ C = pbuf + (size_t)z*NPLANE;

  auto STAGE = [&](int buf, int k0){
    int kg = kbase + k0;
#pragma unroll
    for (int c = 0; c < 2; ++c){
      int q = c*4 + wid;
      int o = q*1024 + lane*16;
      int row = o >> 7;
      int cb = (o & 127) ^ ((row & 7) << 4);
      async_cp16(Ab + (size_t)(m0 + row)*lda + kg + (cb >> 1), (char*)lsA[buf] + q*1024);
    }
#pragma unroll
    for (int c = 0; c < 4; ++c){
      int q = c*4 + wid;
      int o = q*1024 + lane*16;
      int row = o >> 7;
      int cb = (o & 127) ^ ((row & 7) << 4);
      async_cp16(Bb + (size_t)(n0 + row)*ldb + kg + (cb >> 1), (char*)lsB[buf] + q*1024);
    }
  };

  f32x4 acc[2][4];
#pragma unroll
  for (int a=0;a<2;++a)
#pragma unroll
    for (int b=0;b<4;++b) acc[a][b] = f32x4{0.f,0.f,0.f,0.f};

  STAGE(0, 0);
  __syncthreads();
  for (int kt = 0; kt < 16; ++kt){
    int cur = kt & 1;
    if (kt < 15) STAGE(cur ^ 1, (kt+1)*64);
#pragma unroll
    for (int kk = 0; kk < 2; ++kk){
      bf16x8 af[2], bfr[4];
      int kb = kk*64 + ((lane >> 4) << 4);
#pragma unroll
      for (int fm=0; fm<2; ++fm){
        int r = wm*32 + fm*16 + (lane & 15);
        af[fm] = *(const bf16x8*)((const char*)lsA[cur] + r*128 + (kb ^ ((r & 7) << 4)));
      }
#pragma unroll
      for (int fn=0; fn<4; ++fn){
        int r = wn*64 + fn*16 + (lane & 15);
        bfr[fn] = *(const bf16x8*)((const char*)lsB[cur] + r*128 + (kb ^ ((r & 7) << 4)));
      }
#pragma unroll
      for (int fm=0; fm<2; ++fm)
#pragma unroll
        for (int fn=0; fn<4; ++fn)
          acc[fm][fn] = __builtin_amdgcn_mfma_f32_16x16x32_bf16(af[fm], bfr[fn], acc[fm][fn], 0, 0, 0);
    }
    __syncthreads();
  }

#pragma unroll
  for (int fm=0; fm<2; ++fm)
#pragma unroll
    for (int fn=0; fn<4; ++fn)
#pragma unroll
      for (int r=0; r<4; ++r){
        int row = m0 + wm*32 + fm*16 + ((lane >> 4) << 2) + r;
        int col = n0 + wn*64 + fn*16 + (lane & 15);
        C[(size_t)row*HH + col] = acc[fm][fn][r];
      }
}

// ---------------- chunked deferred STDP GEMM --------------------------------
// Per chunk (5 steps), RMW-accumulate into f32 accumulators (in d_out):
//  w_rec acc += -100*sum_j z(t0+j+1)^T u(t0+j)  +  sum_j u(t0+j+1)^T z(t0+j)
//  w_in  acc += sum_j z^T (0.01 tp_i) + sum_j u^T (-1e-4 x)   (scales in slabs)
// Ring slot of time tt is tt mod 6; s0 = t0 mod 6.
__global__ void __launch_bounds__(256) gemm_chunk(
    const u16* __restrict__ zRing, const u16* __restrict__ uRing,
    const u16* __restrict__ tpi01s, const u16* __restrict__ xms,
    int s0, float* __restrict__ o_wrec, float* __restrict__ o_win)
{
  __shared__ u16 lsA[2][128*64];
  __shared__ u16 lsB[2][128*64];
  const int tid = threadIdx.x, lane = tid & 63, wid = tid >> 6;
  const int wm = wid & 1, wn = wid >> 1;

  int bid = blockIdx.x;
  int oid = (bid & 7)*160 + (bid >> 3);    // bijective: 1280 = 8*160
  const bool isrec = (oid < 1024);
  int m0, n0, ldc; float* C;
  if (isrec){ m0 = (oid >> 5)*128; n0 = (oid & 31)*128; C = o_wrec; ldc = HH; }
  else { int r = oid - 1024; m0 = (r >> 3)*128; n0 = (r & 7)*128; C = o_win; ldc = II; }

  auto resolve = [&](int kt, const u16*& A, const u16*& B, int& k0){
    int ph = (kt >= 4*TC);
    int rr = kt - (ph ? 4*TC : 0);
    int j  = rr >> 2;
    k0 = (rr & 3) << 6;
    int sA = s0 + j + 1; if (sA >= NSLOT) sA -= NSLOT;
    int sB = s0 + j;     if (sB >= NSLOT) sB -= NSLOT;
    if (isrec){
      A = (ph ? uRing : zRing) + (size_t)sA*HB;
      B = (ph ? zRing : uRing) + (size_t)sB*HB;
    } else {
      A = (ph ? uRing : zRing) + (size_t)sA*HB;
      B = (ph ? xms : tpi01s) + (size_t)sA*IB;
    }
  };

  auto STAGE = [&](int buf, int kt){
    const u16 *A, *B; int k0;
    resolve(kt, A, B, k0);
#pragma unroll
    for (int c = 0; c < 4; ++c){
      int q = c*4 + wid;
      int o = q*1024 + lane*16;
      int row = o >> 7;
      int cb = (o & 127) ^ ((row & 7) << 4);
      async_cp16(A + (size_t)(m0 + row)*BB + k0 + (cb >> 1), (char*)lsA[buf] + q*1024);
      async_cp16(B + (size_t)(n0 + row)*BB + k0 + (cb >> 1), (char*)lsB[buf] + q*1024);
    }
  };

  f32x4 acc[4][4];
#pragma unroll
  for (int a=0;a<4;++a)
#pragma unroll
    for (int b=0;b<4;++b) acc[a][b] = f32x4{0.f,0.f,0.f,0.f};

  STAGE(0, 0);
  __syncthreads();
  for (int kt = 0; kt < 8*TC; ++kt){
    int cur = kt & 1;
    if (kt < 8*TC-1) STAGE(cur ^ 1, kt+1);
    if (isrec && kt == 4*TC){       // phase switch: acc = S1 -> -100*S1
#pragma unroll
      for (int a=0;a<4;++a)
#pragma unroll
        for (int b=0;b<4;++b)
#pragma unroll
          for (int r=0;r<4;++r) acc[a][b][r] *= -100.f;
    }
#pragma unroll
    for (int kk = 0; kk < 2; ++kk){
      bf16x8 af[4], bfr[4];
      int kb = kk*64 + ((lane >> 4) << 4);
#pragma unroll
      for (int f=0; f<4; ++f){
        int ra = wm*64 + f*16 + (lane & 15);
        af[f] = *(const bf16x8*)((const char*)lsA[cur] + ra*128 + (kb ^ ((ra & 7) << 4)));
        int rb = wn*64 + f*16 + (lane & 15);
        bfr[f] = *(const bf16x8*)((const char*)lsB[cur] + rb*128 + (kb ^ ((rb & 7) << 4)));
      }
#pragma unroll
      for (int fm=0; fm<4; ++fm)
#pragma unroll
        for (int fn=0; fn<4; ++fn)
          acc[fm][fn] = __builtin_amdgcn_mfma_f32_16x16x32_bf16(af[fm], bfr[fn], acc[fm][fn], 0, 0, 0);
    }
    __syncthreads();
  }

#pragma unroll
  for (int fm=0; fm<4; ++fm)
#pragma unroll
    for (int fn=0; fn<4; ++fn)
#pragma unroll
      for (int r=0; r<4; ++r){
        int row = m0 + wm*64 + fm*16 + ((lane >> 4) << 2) + r;
        int col = n0 + wn*64 + fn*16 + (lane & 15);
        C[(size_t)row*ldc + col] += acc[fm][fn][r];
      }
}

// ---------------- prep body: x cast + tp_i filter + scaled transposed slabs -
__device__ __forceinline__ void prep_body(
    const float* __restrict__ x, int t, int i0, int b0, int tid,
    u16* __restrict__ xb_buf, float* __restrict__ tpi,
    u16* __restrict__ tpi01s, u16* __restrict__ xms, int slot,
    u16 (*ls)[64*17])
{
  u16 vp[4], vx[4];
#pragma unroll
  for (int e=0;e<4;++e){
    int f = e*256 + tid;
    int il = f & 63, bl = f >> 6;
    size_t ix = ((size_t)t*BB + b0+bl)*II + i0 + il;
    size_t is = (size_t)(b0+bl)*II + i0 + il;
    float xv = x[ix];
    xb_buf[is] = f2bf(xv);
    float p = tpi[is]; p += 0.0005f*(0.001f*xv - p); tpi[is] = p;
    vp[e] = f2bf(0.01f * p);       // fold +ETA_PLUS
    vx[e] = f2bf(-1e-4f * xv);     // fold -ETA_MINUS
  }
#pragma unroll
  for (int e=0;e<4;++e){
    int f=e*256+tid; int il=f&63, bl=f>>6; int o = il*17+bl;
    ls[0][o]=vp[e]; ls[1][o]=vx[e];
  }
  __syncthreads();
#pragma unroll
  for (int e=0;e<4;++e){
    int f=e*256+tid; int bl=f&15, il=f>>4; int o=il*17+bl;
    size_t oi = (size_t)slot*IB + (size_t)(i0+il)*BB + b0 + bl;
    tpi01s[oi]=ls[0][o]; xms[oi]=ls[1][o];
  }
}

__global__ void __launch_bounds__(256) prep0(
    const float* __restrict__ x, u16* __restrict__ xb_buf,
    float* __restrict__ tpi, u16* __restrict__ tpi01s, u16* __restrict__ xms)
{
  __shared__ u16 ls[2][64*17];
  int bid = blockIdx.x;
  prep_body(x, 0, (bid & 15)*64, (bid >> 4)*16, threadIdx.x,
            xb_buf, tpi, tpi01s, xms, 1, ls);
}

// ---------------- per-step state + ring slabs + (merged) next-step prep -----
__global__ void __launch_bounds__(256) step_state(
    const float* __restrict__ pbuf,
    float* __restrict__ v, float* __restrict__ iS, float* __restrict__ sc,
    float* __restrict__ u,
    u16* __restrict__ zb, u16* __restrict__ zRing, u16* __restrict__ uRing,
    int slotZ,
    const float* __restrict__ x, int tnext, int do_prep,
    u16* __restrict__ xb_buf, float* __restrict__ tpi,
    u16* __restrict__ tpi01s, u16* __restrict__ xms, int slotP)
{
  __shared__ u16 ls[2][64*17];
  const int tid = threadIdx.x;
  const int bid = blockIdx.x;

  if (bid < 1024){
    const int h0 = (bid & 63) * 64;
    const int b0 = (bid >> 6) * 16;
    u16 vz[4], vu[4];
#pragma unroll
    for (int e=0;e<4;++e){
      int f = e*256 + tid;
      int hl = f & 63, bl = f >> 6;
      size_t idx = (size_t)(b0+bl)*HH + h0 + hl;
      float ic = pbuf[idx] + pbuf[idx + NPLANE] + pbuf[idx + 2*NPLANE]
               + pbuf[idx + 3*NPLANE] + pbuf[idx + 4*NPLANE];
      float vv = v[idx], ii = iS[idx];
      float vdec = vv + 0.05f*((0.0f - vv) + ii);
      float idec = ii - 0.1f*ii;
      float z = (vdec >= 0.5f) ? 1.0f : 0.0f;
      v[idx] = (vdec >= 0.5f) ? 0.0f : vdec;
      iS[idx] = idec + ic;
      float uu = u[idx]; uu += 0.0005f*(0.001f*z - uu); u[idx] = uu;
      sc[idx] += z;
      u16 zb16 = f2bf(z);
      zb[idx] = zb16;
      vz[e] = zb16;
      vu[e] = f2bf(uu);
    }
#pragma unroll
    for (int e=0;e<4;++e){
      int f=e*256+tid; int hl=f&63, bl=f>>6; int o = hl*17+bl;
      ls[0][o]=vz[e]; ls[1][o]=vu[e];
    }
    __syncthreads();
#pragma unroll
    for (int e=0;e<4;++e){
      int f=e*256+tid; int bl=f&15, hl=f>>4; int o=hl*17+bl;
      size_t oi = (size_t)slotZ*HB + (size_t)(h0+hl)*BB + b0 + bl;
      zRing[oi]=ls[0][o]; uRing[oi]=ls[1][o];
    }
  } else {
    if (!do_prep) return;
    int r = bid - 1024;
    prep_body(x, tnext, (r & 15)*64, (r >> 4)*16, tid,
              xb_buf, tpi, tpi01s, xms, slotP, ls);
  }
}

// ---------------- casts and finalize ----------------------------------------
__global__ void __launch_bounds__(256) cast_bf(const f32x4* __restrict__ w0,
                                               u16x4* __restrict__ wb, long long n4){
  long long i = (long long)blockIdx.x*blockDim.x + threadIdx.x;
  long long stride = (long long)gridDim.x*blockDim.x;
  for (; i < n4; i += stride){
    f32x4 vv = w0[i];
    u16x4 o;
#pragma unroll
    for (int j=0;j<4;++j) o[j] = f2bf(vv[j]);
    wb[i] = o;
  }
}

// acc = w0 + scale*acc  (o_wrec: scale=-1e-4 ; o_win: scale=1)
__global__ void __launch_bounds__(256) fin_w(const f32x4* __restrict__ w0,
                                             f32x4* __restrict__ acc,
                                             float scale, long long n4){
  long long i = (long long)blockIdx.x*blockDim.x + threadIdx.x;
  long long stride = (long long)gridDim.x*blockDim.x;
  for (; i < n4; i += stride){
    f32x4 a = acc[i], w = w0[i];
#pragma unroll
    for (int j=0;j<4;++j) a[j] = w[j] + scale*a[j];
    acc[i] = a;
  }
}

__global__ void __launch_bounds__(256) fin_logits(const float* __restrict__ sc,
                                                  float* __restrict__ logits, float* __restrict__ total){
  __shared__ float bins[LL];
  const int tid = threadIdx.x;
  const int b = blockIdx.x;
  if (tid < LL) bins[tid] = 0.f;
  __syncthreads();
#pragma unroll
  for (int e=0;e<16;++e){
    int h = e*256 + tid;
    float vv = sc[(size_t)b*HH + h];
    int a = h/409; if (a > 9) a = 9;
    atomicAdd(&bins[a], vv);
  }
  __syncthreads();
  if (tid < LL){
    float cnt = (tid==9) ? 415.f : 409.f;
    logits[b*LL + tid] = bins[tid] / (50.f * cnt);
  }
  if (tid == 0){
    float s = 0.f;
    for (int l=0;l<LL;++l) s += bins[l];
    atomicAdd(total, s);
  }
}

__global__ void __launch_bounds__(256) fin_spikecnt(const float* __restrict__ sc,
                                                    const int* __restrict__ label, float* __restrict__ out){
  int h = blockIdx.x*256 + threadIdx.x;
  int bs = blockIdx.y*32;
  float acc[LL];
#pragma unroll
  for (int j=0;j<LL;++j) acc[j] = 0.f;
  for (int b=bs; b<bs+32; ++b){
    int l = label[b];
    float vv = sc[(size_t)b*HH + h];
#pragma unroll
    for (int j=0;j<LL;++j) acc[j] += (j==l) ? vv : 0.f;
  }
#pragma unroll
  for (int j=0;j<LL;++j)
    if (acc[j] != 0.f) atomicAdd(&out[(size_t)j*HH + h], acc[j]);
}

__global__ void __launch_bounds__(256) fin_labelcnt(const int* __restrict__ label, float* __restrict__ out){
  __shared__ int bins[LL];
  const int tid = threadIdx.x;
  if (tid < LL) bins[tid] = 0;
  __syncthreads();
  atomicAdd(&bins[label[tid]], 1);
  __syncthreads();
  if (tid < LL) out[tid] = 50.f * (float)bins[tid];
}

extern "C" void kernel_launch(void* const* d_in, const int* in_sizes, int n_in,
                              void* d_out, int out_size, void* d_ws, size_t ws_size,
                              hipStream_t stream)
{
  (void)in_sizes; (void)n_in; (void)out_size; (void)ws_size;
  const float* x      = (const float*)d_in[0];
  const int*   label  = (const int*)d_in[1];
  const float* w_in0  = (const float*)d_in[2];
  const float* w_rec0 = (const float*)d_in[3];

  float* out      = (float*)d_out;
  float* o_logits = out;                            // 2560
  float* o_total  = out + 2560;                     // 1
  float* o_win    = out + 2561;                     // H*I f32 accumulator -> final
  float* o_wrec   = o_win + (size_t)HH*II;          // H*H f32 accumulator -> final
  float* o_sc     = o_wrec + (size_t)HH*HH;         // L*H
  float* o_lc     = o_sc + (size_t)LL*HH;           // L

  char* cur = (char*)d_ws;
  auto alloc = [&](size_t bytes)->char*{ char* p = cur; cur += (bytes + 255) & ~(size_t)255; return p; };
  u16*   wib    = (u16*)  alloc((size_t)HH*II*2);        //  8.4 MB
  u16*   wrb    = (u16*)  alloc((size_t)HH*HH*2);        // 33.6 MB
  float* v      = (float*)alloc(NPLANE*4);               //  4.2
  float* iS     = (float*)alloc(NPLANE*4);               //  4.2
  float* sc     = (float*)alloc(NPLANE*4);               //  4.2
  float* u      = (float*)alloc(NPLANE*4);               //  4.2
  float* pbuf   = (float*)alloc(5*NPLANE*4);             // 21.0
  u16*   zb     = (u16*)  alloc(NPLANE*2);               //  2.1
  u16*   xb_buf = (u16*)  alloc((size_t)BB*II*2);        //  0.5
  float* tpi    = (float*)alloc((size_t)BB*II*4);        //  1.0
  u16*   zRing  = (u16*)  alloc((size_t)NSLOT*HB*2);     // 12.6
  u16*   uRing  = (u16*)  alloc((size_t)NSLOT*HB*2);     // 12.6
  u16*   tpi01s = (u16*)  alloc((size_t)NSLOT*IB*2);     //  3.1
  u16*   xms    = (u16*)  alloc((size_t)NSLOT*IB*2);     //  3.1
                                                         // total ~115 MB

  hipMemsetAsync(v,     0, NPLANE*4, stream);
  hipMemsetAsync(iS,    0, NPLANE*4, stream);
  hipMemsetAsync(sc,    0, NPLANE*4, stream);
  hipMemsetAsync(u,     0, NPLANE*4, stream);
  hipMemsetAsync(zb,    0, NPLANE*2, stream);
  hipMemsetAsync(tpi,   0, (size_t)BB*II*4, stream);
  hipMemsetAsync(zRing, 0, HB*2, stream);                // slot 0 = z(0) = 0
  hipMemsetAsync(uRing, 0, HB*2, stream);                // slot 0 = u(0) = 0
  hipMemsetAsync(o_win, 0, (size_t)HH*II*4, stream);     // f32 accumulator
  hipMemsetAsync(o_wrec,0, (size_t)HH*HH*4, stream);     // f32 accumulator
  hipMemsetAsync(o_total, 0, 4, stream);
  hipMemsetAsync(o_sc,  0, (size_t)LL*HH*4, stream);

  cast_bf<<<1024, 256, 0, stream>>>((const f32x4*)w_in0,  (u16x4*)wib, (long long)HH*II/4);
  cast_bf<<<2048, 256, 0, stream>>>((const f32x4*)w_rec0, (u16x4*)wrb, (long long)HH*HH/4);
  prep0<<<256, 256, 0, stream>>>(x, xb_buf, tpi, tpi01s, xms);

  for (int t = 0; t < TSTEPS; ++t){
    gemm_fwd<<<640, 256, 0, stream>>>(xb_buf, wib, zb, wrb, pbuf);

    step_state<<<1280, 256, 0, stream>>>(
        pbuf, v, iS, sc, u, zb, zRing, uRing, (t+1) % NSLOT,
        x, t+1, (t < TSTEPS-1) ? 1 : 0,
        xb_buf, tpi, tpi01s, xms, (t+2) % NSLOT);

    if ((t+1) % TC == 0){
      int s0 = (t+1-TC) % NSLOT;
      gemm_chunk<<<1280, 256, 0, stream>>>(zRing, uRing, tpi01s, xms,
                                           s0, o_wrec, o_win);
    }
  }

  fin_w<<<2048, 256, 0, stream>>>((const f32x4*)w_rec0, (f32x4*)o_wrec, -1e-4f, (long long)HH*HH/4);
  fin_w<<<1024, 256, 0, stream>>>((const f32x4*)w_in0,  (f32x4*)o_win,  1.0f,   (long long)HH*II/4);

  fin_logits  <<<BB, 256, 0, stream>>>(sc, o_logits, o_total);
  fin_spikecnt<<<dim3(HH/256, 8), 256, 0, stream>>>(sc, label, o_sc);
  fin_labelcnt<<<1, 256, 0, stream>>>(label, o_lc);
}

// Round 6
// 3176.487 us; speedup vs baseline: 1.9570x; 1.0056x over previous
//
#include <hip/hip_runtime.h>

typedef unsigned short u16;
typedef unsigned int u32;
typedef __attribute__((ext_vector_type(4))) float f32x4;
typedef __attribute__((ext_vector_type(4))) u16 u16x4;
typedef __attribute__((ext_vector_type(8))) __bf16 bf16x8;

#define TSTEPS 50
#define BB 256
#define II 1024
#define HH 4096
#define LL 10
#define NPLANE ((size_t)BB*HH)
#define HB ((size_t)HH*BB)
#define IB ((size_t)II*BB)
#define TC 5          // chunk length
#define NSLOT 8       // ring slots (power of 2)

__device__ __forceinline__ u16 f2bf(float f){
  u32 u = __float_as_uint(f);
  u += 0x7fffu + ((u >> 16) & 1u);
  return (u16)(u >> 16);
}
__device__ __forceinline__ float bf2f(u16 u){ return __uint_as_float(((u32)u) << 16); }

__device__ __forceinline__ void async_cp16(const void* g, void* l){
  auto gp = (const __attribute__((address_space(1))) void*)(unsigned long long)(g);
  auto lp = (__attribute__((address_space(3))) void*)(unsigned int)(unsigned long long)(l);
  __builtin_amdgcn_global_load_lds(gp, lp, 16, 0, 0);
}

// ---------------- forward: split-K over 5 planes of K=1024 ------------------
// plane 0: x_t @ w_in0^T ; planes 1..4: z_old @ w_rec0^T (frozen bf16 weights)
__global__ void __launch_bounds__(256) gemm_fwd(
    const u16* __restrict__ xbt, const u16* __restrict__ wib,
    const u16* __restrict__ zb,  const u16* __restrict__ wrb,
    float* __restrict__ pbuf)
{
  __shared__ u16 lsA[2][64*64];
  __shared__ u16 lsB[2][128*64];
  const int tid = threadIdx.x, lane = tid & 63, wid = tid >> 6;
  const int wm = wid & 1, wn = wid >> 1;

  int bid = blockIdx.x;
  int oid = (bid & 7)*80 + (bid >> 3);     // bijective: 640 = 8*80
  int z   = oid >> 7;
  int rem = oid & 127;
  int n0  = (rem >> 2) * 128;
  int m0  = (rem & 3) * 64;

  const u16* __restrict__ Ab; const u16* __restrict__ Bb;
  int lda, ldb, kbase;
  if (z == 0){ Ab = xbt; lda = II; Bb = wib; ldb = II; kbase = 0; }
  else       { Ab = zb;  lda = HH; Bb = wrb; ldb = HH; kbase = (z-1)*1024; }
  float* __restrict__ C = pbuf + (size_t)z*NPLANE;

  auto STAGE = [&](int buf, int k0){
    int kg = kbase + k0;
#pragma unroll
    for (int c = 0; c < 2; ++c){
      int q = c*4 + wid;
      int o = q*1024 + lane*16;
      int row = o >> 7;
      int cb = (o & 127) ^ ((row & 7) << 4);
      async_cp16(Ab + (size_t)(m0 + row)*lda + kg + (cb >> 1), (char*)lsA[buf] + q*1024);
    }
#pragma unroll
    for (int c = 0; c < 4; ++c){
      int q = c*4 + wid;
      int o = q*1024 + lane*16;
      int row = o >> 7;
      int cb = (o & 127) ^ ((row & 7) << 4);
      async_cp16(Bb + (size_t)(n0 + row)*ldb + kg + (cb >> 1), (char*)lsB[buf] + q*1024);
    }
  };

  f32x4 acc[2][4];
#pragma unroll
  for (int a=0;a<2;++a)
#pragma unroll
    for (int b=0;b<4;++b) acc[a][b] = f32x4{0.f,0.f,0.f,0.f};

  STAGE(0, 0);
  __syncthreads();
  for (int kt = 0; kt < 16; ++kt){
    int cur = kt & 1;
    if (kt < 15) STAGE(cur ^ 1, (kt+1)*64);
#pragma unroll
    for (int kk = 0; kk < 2; ++kk){
      bf16x8 af[2], bfr[4];
      int kb = kk*64 + ((lane >> 4) << 4);
#pragma unroll
      for (int fm=0; fm<2; ++fm){
        int r = wm*32 + fm*16 + (lane & 15);
        af[fm] = *(const bf16x8*)((const char*)lsA[cur] + r*128 + (kb ^ ((r & 7) << 4)));
      }
#pragma unroll
      for (int fn=0; fn<4; ++fn){
        int r = wn*64 + fn*16 + (lane & 15);
        bfr[fn] = *(const bf16x8*)((const char*)lsB[cur] + r*128 + (kb ^ ((r & 7) << 4)));
      }
#pragma unroll
      for (int fm=0; fm<2; ++fm)
#pragma unroll
        for (int fn=0; fn<4; ++fn)
          acc[fm][fn] = __builtin_amdgcn_mfma_f32_16x16x32_bf16(af[fm], bfr[fn], acc[fm][fn], 0, 0, 0);
    }
    __syncthreads();
  }

#pragma unroll
  for (int fm=0; fm<2; ++fm)
#pragma unroll
    for (int fn=0; fn<4; ++fn)
#pragma unroll
      for (int r=0; r<4; ++r){
        int row = m0 + wm*32 + fm*16 + ((lane >> 4) << 2) + r;
        int col = n0 + wn*64 + fn*16 + (lane & 15);
        C[(size_t)row*HH + col] = acc[fm][fn][r];
      }
}

// ---------------- chunked deferred STDP GEMM (single-buffer, m97 structure) -
// Per chunk (5 steps), accumulate into f32 accumulators (in d_out):
//  w_rec acc += -100*sum_j z(t0+j+1)^T u(t0+j)  +  sum_j u(t0+j+1)^T z(t0+j)
//  w_in  acc += sum_j z^T (0.01 tp_i) + sum_j u^T (-1e-4 x)   (scales in slabs)
__global__ void __launch_bounds__(256) gemm_chunk(
    const u16* __restrict__ zRing, const u16* __restrict__ uRing,
    const u16* __restrict__ tpi01s, const u16* __restrict__ xms,
    int s0, int first, float* __restrict__ o_wrec, float* __restrict__ o_win)
{
  __shared__ u16 lsA[128*64];   // 16 KB
  __shared__ u16 lsB[128*64];   // 16 KB
  const int tid = threadIdx.x, lane = tid & 63, wid = tid >> 6;
  const int wm = wid & 1, wn = wid >> 1;
  const int xcd = blockIdx.x & 7;
  const int local = blockIdx.x >> 3;
  const bool isrec = (local < 128);

  int m0, n0, ldc; float* C;
  if (isrec){                    // w_rec: per-XCD 8x16 tile rectangle
    int tm = (xcd >> 1)*8 + (local & 7);
    int tn = (xcd & 1)*16 + (local >> 3);
    m0 = tm*128; n0 = tn*128; C = o_wrec; ldc = HH;
  } else {                       // w_in: per-XCD 8x4 tile rectangle
    int l2 = local - 128;
    int tm = (xcd >> 1)*8 + (l2 & 7);
    int tn = (xcd & 1)*4 + (l2 >> 3);
    m0 = tm*128; n0 = tn*128; C = o_win; ldc = II;
  }

  // staging invariants (lane-dependent swizzle, hoisted out of the K loop)
  int offA[4], offB[4], ldso[4];
#pragma unroll
  for (int c=0;c<4;++c){
    int q = c*4 + wid;
    int o = q*1024 + lane*16;
    int row = o >> 7;
    int cb = (o & 127) ^ ((row & 7) << 4);
    offA[c] = (m0 + row)*BB + (cb >> 1);
    offB[c] = (n0 + row)*BB + (cb >> 1);
    ldso[c] = q*1024;
  }

  f32x4 acc[4][4];
#pragma unroll
  for (int a=0;a<4;++a)
#pragma unroll
    for (int b=0;b<4;++b) acc[a][b] = f32x4{0.f,0.f,0.f,0.f};

#pragma unroll
  for (int ph = 0; ph < 2; ++ph){
    if (ph == 1 && isrec){        // phase switch: acc = S1 -> -100*S1
#pragma unroll
      for (int a=0;a<4;++a)
#pragma unroll
        for (int b=0;b<4;++b)
#pragma unroll
          for (int r=0;r<4;++r) acc[a][b][r] *= -100.f;
    }
#pragma unroll
    for (int j = 0; j < TC; ++j){
      int sA = (s0 + j + 1) & (NSLOT-1);
      int sB = (s0 + j) & (NSLOT-1);
      const u16* __restrict__ Aslab = (ph ? uRing : zRing) + (size_t)sA*HB;
      const u16* __restrict__ Bslab = isrec
          ? ((ph ? zRing : uRing) + (size_t)sB*HB)
          : ((ph ? xms : tpi01s) + (size_t)sA*IB);
#pragma unroll 1
      for (int kq = 0; kq < 4; ++kq){
        int k0 = kq << 6;
#pragma unroll
        for (int c=0;c<4;++c){
          async_cp16(Aslab + offA[c] + k0, (char*)lsA + ldso[c]);
          async_cp16(Bslab + offB[c] + k0, (char*)lsB + ldso[c]);
        }
        __syncthreads();          // drains staging (vmcnt 0) + barrier
#pragma unroll
        for (int kk = 0; kk < 2; ++kk){
          bf16x8 af[4], bfr[4];
          int kb = kk*64 + ((lane >> 4) << 4);
#pragma unroll
          for (int f=0; f<4; ++f){
            int ra = wm*64 + f*16 + (lane & 15);
            af[f] = *(const bf16x8*)((const char*)lsA + ra*128 + (kb ^ ((ra & 7) << 4)));
            int rb = wn*64 + f*16 + (lane & 15);
            bfr[f] = *(const bf16x8*)((const char*)lsB + rb*128 + (kb ^ ((rb & 7) << 4)));
          }
#pragma unroll
          for (int fm=0; fm<4; ++fm)
#pragma unroll
            for (int fn=0; fn<4; ++fn)
              acc[fm][fn] = __builtin_amdgcn_mfma_f32_16x16x32_bf16(af[fm], bfr[fn], acc[fm][fn], 0, 0, 0);
        }
        __syncthreads();          // protect LDS before next stage
      }
    }
  }

  if (first){
#pragma unroll
    for (int fm=0; fm<4; ++fm)
#pragma unroll
      for (int fn=0; fn<4; ++fn)
#pragma unroll
        for (int r=0; r<4; ++r){
          int row = m0 + wm*64 + fm*16 + ((lane >> 4) << 2) + r;
          int col = n0 + wn*64 + fn*16 + (lane & 15);
          C[(size_t)row*ldc + col] = acc[fm][fn][r];
        }
  } else {
#pragma unroll
    for (int fm=0; fm<4; ++fm)
#pragma unroll
      for (int fn=0; fn<4; ++fn)
#pragma unroll
        for (int r=0; r<4; ++r){
          int row = m0 + wm*64 + fm*16 + ((lane >> 4) << 2) + r;
          int col = n0 + wn*64 + fn*16 + (lane & 15);
          C[(size_t)row*ldc + col] += acc[fm][fn][r];
        }
  }
}

// ---------------- prep body: x cast + tp_i filter + scaled transposed slabs -
__device__ __forceinline__ void prep_body(
    const float* __restrict__ x, int t, int i0, int b0, int tid,
    u16* __restrict__ xb_buf, float* __restrict__ tpi,
    u16* __restrict__ tpi01s, u16* __restrict__ xms, int slot,
    u16 (*ls)[64*17])
{
  u16 vp[4], vx[4];
#pragma unroll
  for (int e=0;e<4;++e){
    int f = e*256 + tid;
    int il = f & 63, bl = f >> 6;
    size_t ix = ((size_t)t*BB + b0+bl)*II + i0 + il;
    size_t is = (size_t)(b0+bl)*II + i0 + il;
    float xv = x[ix];
    xb_buf[is] = f2bf(xv);
    float p = tpi[is]; p += 0.0005f*(0.001f*xv - p); tpi[is] = p;
    vp[e] = f2bf(0.01f * p);       // fold +ETA_PLUS
    vx[e] = f2bf(-1e-4f * xv);     // fold -ETA_MINUS
  }
#pragma unroll
  for (int e=0;e<4;++e){
    int f=e*256+tid; int il=f&63, bl=f>>6; int o = il*17+bl;
    ls[0][o]=vp[e]; ls[1][o]=vx[e];
  }
  __syncthreads();
#pragma unroll
  for (int e=0;e<4;++e){
    int f=e*256+tid; int bl=f&15, il=f>>4; int o=il*17+bl;
    size_t oi = (size_t)slot*IB + (size_t)(i0+il)*BB + b0 + bl;
    tpi01s[oi]=ls[0][o]; xms[oi]=ls[1][o];
  }
}

__global__ void __launch_bounds__(256) prep0(
    const float* __restrict__ x, u16* __restrict__ xb_buf,
    float* __restrict__ tpi, u16* __restrict__ tpi01s, u16* __restrict__ xms)
{
  __shared__ u16 ls[2][64*17];
  int bid = blockIdx.x;
  prep_body(x, 0, (bid & 15)*64, (bid >> 4)*16, threadIdx.x,
            xb_buf, tpi, tpi01s, xms, 1, ls);
}

// ---------------- per-step state + ring slabs + (merged) next-step prep -----
__global__ void __launch_bounds__(256) step_state(
    const float* __restrict__ pbuf,
    float* __restrict__ v, float* __restrict__ iS, float* __restrict__ sc,
    float* __restrict__ u,
    u16* __restrict__ zb, u16* __restrict__ zRing, u16* __restrict__ uRing,
    int slotZ,
    const float* __restrict__ x, int tnext, int do_prep,
    u16* __restrict__ xb_buf, float* __restrict__ tpi,
    u16* __restrict__ tpi01s, u16* __restrict__ xms, int slotP)
{
  __shared__ u16 ls[2][64*17];
  const int tid = threadIdx.x;
  const int bid = blockIdx.x;

  if (bid < 1024){
    const int h0 = (bid & 63) * 64;
    const int b0 = (bid >> 6) * 16;
    u16 vz[4], vu[4];
#pragma unroll
    for (int e=0;e<4;++e){
      int f = e*256 + tid;
      int hl = f & 63, bl = f >> 6;
      size_t idx = (size_t)(b0+bl)*HH + h0 + hl;
      float ic = pbuf[idx] + pbuf[idx + NPLANE] + pbuf[idx + 2*NPLANE]
               + pbuf[idx + 3*NPLANE] + pbuf[idx + 4*NPLANE];
      float vv = v[idx], ii = iS[idx];
      float vdec = vv + 0.05f*((0.0f - vv) + ii);
      float idec = ii - 0.1f*ii;
      float z = (vdec >= 0.5f) ? 1.0f : 0.0f;
      v[idx] = (vdec >= 0.5f) ? 0.0f : vdec;
      iS[idx] = idec + ic;
      float uu = u[idx]; uu += 0.0005f*(0.001f*z - uu); u[idx] = uu;
      sc[idx] += z;
      u16 zb16 = f2bf(z);
      zb[idx] = zb16;
      vz[e] = zb16;
      vu[e] = f2bf(uu);
    }
#pragma unroll
    for (int e=0;e<4;++e){
      int f=e*256+tid; int hl=f&63, bl=f>>6; int o = hl*17+bl;
      ls[0][o]=vz[e]; ls[1][o]=vu[e];
    }
    __syncthreads();
#pragma unroll
    for (int e=0;e<4;++e){
      int f=e*256+tid; int bl=f&15, hl=f>>4; int o=hl*17+bl;
      size_t oi = (size_t)slotZ*HB + (size_t)(h0+hl)*BB + b0 + bl;
      zRing[oi]=ls[0][o]; uRing[oi]=ls[1][o];
    }
  } else {
    if (!do_prep) return;
    int r = bid - 1024;
    prep_body(x, tnext, (r & 15)*64, (r >> 4)*16, tid,
              xb_buf, tpi, tpi01s, xms, slotP, ls);
  }
}

// ---------------- casts and finalize ----------------------------------------
__global__ void __launch_bounds__(256) cast_bf(const f32x4* __restrict__ w0,
                                               u16x4* __restrict__ wb, long long n4){
  long long i = (long long)blockIdx.x*blockDim.x + threadIdx.x;
  long long stride = (long long)gridDim.x*blockDim.x;
  for (; i < n4; i += stride){
    f32x4 vv = w0[i];
    u16x4 o;
#pragma unroll
    for (int j=0;j<4;++j) o[j] = f2bf(vv[j]);
    wb[i] = o;
  }
}

// acc = w0 + scale*acc  (o_wrec: scale=-1e-4 ; o_win: scale=1)
__global__ void __launch_bounds__(256) fin_w(const f32x4* __restrict__ w0,
                                             f32x4* __restrict__ acc,
                                             float scale, long long n4){
  long long i = (long long)blockIdx.x*blockDim.x + threadIdx.x;
  long long stride = (long long)gridDim.x*blockDim.x;
  for (; i < n4; i += stride){
    f32x4 a = acc[i], w = w0[i];
#pragma unroll
    for (int j=0;j<4;++j) a[j] = w[j] + scale*a[j];
    acc[i] = a;
  }
}

__global__ void __launch_bounds__(256) fin_logits(const float* __restrict__ sc,
                                                  float* __restrict__ logits, float* __restrict__ total){
  __shared__ float bins[LL];
  const int tid = threadIdx.x;
  const int b = blockIdx.x;
  if (tid < LL) bins[tid] = 0.f;
  __syncthreads();
#pragma unroll
  for (int e=0;e<16;++e){
    int h = e*256 + tid;
    float vv = sc[(size_t)b*HH + h];
    int a = h/409; if (a > 9) a = 9;
    atomicAdd(&bins[a], vv);
  }
  __syncthreads();
  if (tid < LL){
    float cnt = (tid==9) ? 415.f : 409.f;
    logits[b*LL + tid] = bins[tid] / (50.f * cnt);
  }
  if (tid == 0){
    float s = 0.f;
    for (int l=0;l<LL;++l) s += bins[l];
    atomicAdd(total, s);
  }
}

__global__ void __launch_bounds__(256) fin_spikecnt(const float* __restrict__ sc,
                                                    const int* __restrict__ label, float* __restrict__ out){
  int h = blockIdx.x*256 + threadIdx.x;
  int bs = blockIdx.y*32;
  float acc[LL];
#pragma unroll
  for (int j=0;j<LL;++j) acc[j] = 0.f;
  for (int b=bs; b<bs+32; ++b){
    int l = label[b];
    float vv = sc[(size_t)b*HH + h];
#pragma unroll
    for (int j=0;j<LL;++j) acc[j] += (j==l) ? vv : 0.f;
  }
#pragma unroll
  for (int j=0;j<LL;++j)
    if (acc[j] != 0.f) atomicAdd(&out[(size_t)j*HH + h], acc[j]);
}

__global__ void __launch_bounds__(256) fin_labelcnt(const int* __restrict__ label, float* __restrict__ out){
  __shared__ int bins[LL];
  const int tid = threadIdx.x;
  if (tid < LL) bins[tid] = 0;
  __syncthreads();
  atomicAdd(&bins[label[tid]], 1);
  __syncthreads();
  if (tid < LL) out[tid] = 50.f * (float)bins[tid];
}

extern "C" void kernel_launch(void* const* d_in, const int* in_sizes, int n_in,
                              void* d_out, int out_size, void* d_ws, size_t ws_size,
                              hipStream_t stream)
{
  (void)in_sizes; (void)n_in; (void)out_size; (void)ws_size;
  const float* x      = (const float*)d_in[0];
  const int*   label  = (const int*)d_in[1];
  const float* w_in0  = (const float*)d_in[2];
  const float* w_rec0 = (const float*)d_in[3];

  float* out      = (float*)d_out;
  float* o_logits = out;                            // 2560
  float* o_total  = out + 2560;                     // 1
  float* o_win    = out + 2561;                     // H*I f32 accumulator -> final
  float* o_wrec   = o_win + (size_t)HH*II;          // H*H f32 accumulator -> final
  float* o_sc     = o_wrec + (size_t)HH*HH;         // L*H
  float* o_lc     = o_sc + (size_t)LL*HH;           // L

  char* cur = (char*)d_ws;
  auto alloc = [&](size_t bytes)->char*{ char* p = cur; cur += (bytes + 255) & ~(size_t)255; return p; };
  u16*   wib    = (u16*)  alloc((size_t)HH*II*2);        //  8.4 MB
  u16*   wrb    = (u16*)  alloc((size_t)HH*HH*2);        // 33.6 MB
  float* v      = (float*)alloc(NPLANE*4);               //  4.2
  float* iS     = (float*)alloc(NPLANE*4);               //  4.2
  float* sc     = (float*)alloc(NPLANE*4);               //  4.2
  float* u      = (float*)alloc(NPLANE*4);               //  4.2
  float* pbuf   = (float*)alloc(5*NPLANE*4);             // 21.0
  u16*   zb     = (u16*)  alloc(NPLANE*2);               //  2.1
  u16*   xb_buf = (u16*)  alloc((size_t)BB*II*2);        //  0.5
  float* tpi    = (float*)alloc((size_t)BB*II*4);        //  1.0
  u16*   zRing  = (u16*)  alloc((size_t)NSLOT*HB*2);     // 16.8
  u16*   uRing  = (u16*)  alloc((size_t)NSLOT*HB*2);     // 16.8
  u16*   tpi01s = (u16*)  alloc((size_t)NSLOT*IB*2);     //  4.2
  u16*   xms    = (u16*)  alloc((size_t)NSLOT*IB*2);     //  4.2
                                                         // total ~123 MB

  hipMemsetAsync(v,     0, NPLANE*4, stream);
  hipMemsetAsync(iS,    0, NPLANE*4, stream);
  hipMemsetAsync(sc,    0, NPLANE*4, stream);
  hipMemsetAsync(u,     0, NPLANE*4, stream);
  hipMemsetAsync(zb,    0, NPLANE*2, stream);
  hipMemsetAsync(tpi,   0, (size_t)BB*II*4, stream);
  hipMemsetAsync(zRing, 0, HB*2, stream);                // slot 0 = z(0) = 0
  hipMemsetAsync(uRing, 0, HB*2, stream);                // slot 0 = u(0) = 0
  hipMemsetAsync(o_total, 0, 4, stream);
  hipMemsetAsync(o_sc,  0, (size_t)LL*HH*4, stream);

  cast_bf<<<1024, 256, 0, stream>>>((const f32x4*)w_in0,  (u16x4*)wib, (long long)HH*II/4);
  cast_bf<<<2048, 256, 0, stream>>>((const f32x4*)w_rec0, (u16x4*)wrb, (long long)HH*HH/4);
  prep0<<<256, 256, 0, stream>>>(x, xb_buf, tpi, tpi01s, xms);

  for (int t = 0; t < TSTEPS; ++t){
    gemm_fwd<<<640, 256, 0, stream>>>(xb_buf, wib, zb, wrb, pbuf);

    step_state<<<1280, 256, 0, stream>>>(
        pbuf, v, iS, sc, u, zb, zRing, uRing, (t+1) & (NSLOT-1),
        x, t+1, (t < TSTEPS-1) ? 1 : 0,
        xb_buf, tpi, tpi01s, xms, (t+2) & (NSLOT-1));

    if ((t+1) % TC == 0){
      int s0 = (t+1-TC) & (NSLOT-1);
      gemm_chunk<<<1280, 256, 0, stream>>>(zRing, uRing, tpi01s, xms,
                                           s0, (t+1 == TC) ? 1 : 0,
                                           o_wrec, o_win);
    }
  }

  fin_w<<<2048, 256, 0, stream>>>((const f32x4*)w_rec0, (f32x4*)o_wrec, -1e-4f, (long long)HH*HH/4);
  fin_w<<<1024, 256, 0, stream>>>((const f32x4*)w_in0,  (f32x4*)o_win,  1.0f,   (long long)HH*II/4);

  fin_logits  <<<BB, 256, 0, stream>>>(sc, o_logits, o_total);
  fin_spikecnt<<<dim3(HH/256, 8), 256, 0, stream>>>(sc, label, o_sc);
  fin_labelcnt<<<1, 256, 0, stream>>>(label, o_lc);
}

// Round 7
// 3074.859 us; speedup vs baseline: 2.0217x; 1.0331x over previous
//
#include <hip/hip_runtime.h>

typedef unsigned short u16;
typedef unsigned int u32;
typedef __attribute__((ext_vector_type(4))) float f32x4;
typedef __attribute__((ext_vector_type(4))) u16 u16x4;
typedef __attribute__((ext_vector_type(8))) __bf16 bf16x8;

#define TSTEPS 50
#define BB 256
#define II 1024
#define HH 4096
#define LL 10
#define NPLANE ((size_t)BB*HH)
#define HB ((size_t)HH*BB)
#define IB ((size_t)II*BB)
#define TC 5          // chunk length
#define NSLOT 8       // ring slots (power of 2)

__device__ __forceinline__ u16 f2bf(float f){
  u32 u = __float_as_uint(f);
  u += 0x7fffu + ((u >> 16) & 1u);
  return (u16)(u >> 16);
}
__device__ __forceinline__ float bf2f(u16 u){ return __uint_as_float(((u32)u) << 16); }

__device__ __forceinline__ void async_cp16(const void* g, void* l){
  auto gp = (const __attribute__((address_space(1))) void*)(unsigned long long)(g);
  auto lp = (__attribute__((address_space(3))) void*)(unsigned int)(unsigned long long)(l);
  __builtin_amdgcn_global_load_lds(gp, lp, 16, 0, 0);
}

// ---------------- forward: split-K over 5 planes of K=1024 ------------------
// plane 0: x_t @ w_in0^T ; planes 1..4: z_old @ w_rec0^T (frozen bf16 weights)
// dbuf + counted vmcnt(6): staging loads stay in flight under the MFMAs.
__global__ void __launch_bounds__(256) gemm_fwd(
    const u16* __restrict__ xbt, const u16* __restrict__ wib,
    const u16* __restrict__ zb,  const u16* __restrict__ wrb,
    float* __restrict__ pbuf)
{
  __shared__ u16 lsA[2][64*64];
  __shared__ u16 lsB[2][128*64];
  const int tid = threadIdx.x, lane = tid & 63, wid = tid >> 6;
  const int wm = wid & 1, wn = wid >> 1;

  int bid = blockIdx.x;
  int oid = (bid & 7)*80 + (bid >> 3);     // bijective: 640 = 8*80
  int z   = oid >> 7;
  int rem = oid & 127;
  int n0  = (rem >> 2) * 128;
  int m0  = (rem & 3) * 64;

  const u16* __restrict__ Ab; const u16* __restrict__ Bb;
  int lda, ldb, kbase;
  if (z == 0){ Ab = xbt; lda = II; Bb = wib; ldb = II; kbase = 0; }
  else       { Ab = zb;  lda = HH; Bb = wrb; ldb = HH; kbase = (z-1)*1024; }
  float* __restrict__ C = pbuf + (size_t)z*NPLANE;

  auto STAGE = [&](int buf, int k0){
    int kg = kbase + k0;
#pragma unroll
    for (int c = 0; c < 2; ++c){
      int q = c*4 + wid;
      int o = q*1024 + lane*16;
      int row = o >> 7;
      int cb = (o & 127) ^ ((row & 7) << 4);
      async_cp16(Ab + (size_t)(m0 + row)*lda + kg + (cb >> 1), (char*)lsA[buf] + q*1024);
    }
#pragma unroll
    for (int c = 0; c < 4; ++c){
      int q = c*4 + wid;
      int o = q*1024 + lane*16;
      int row = o >> 7;
      int cb = (o & 127) ^ ((row & 7) << 4);
      async_cp16(Bb + (size_t)(n0 + row)*ldb + kg + (cb >> 1), (char*)lsB[buf] + q*1024);
    }
  };

  f32x4 acc[2][4];
#pragma unroll
  for (int a=0;a<2;++a)
#pragma unroll
    for (int b=0;b<4;++b) acc[a][b] = f32x4{0.f,0.f,0.f,0.f};

  STAGE(0, 0);
#pragma unroll 1
  for (int kt = 0; kt < 16; ++kt){
    int cur = kt & 1;
    if (kt < 15){
      STAGE(cur ^ 1, (kt+1)*64);                       // 6 loads in flight
      asm volatile("s_waitcnt vmcnt(6)" ::: "memory"); // older 6 (cur buf) landed
    } else {
      asm volatile("s_waitcnt vmcnt(0)" ::: "memory");
    }
    __builtin_amdgcn_s_barrier();                      // all waves' cur loads landed
#pragma unroll
    for (int kk = 0; kk < 2; ++kk){
      bf16x8 af[2], bfr[4];
      int kb = kk*64 + ((lane >> 4) << 4);
#pragma unroll
      for (int fm=0; fm<2; ++fm){
        int r = wm*32 + fm*16 + (lane & 15);
        af[fm] = *(const bf16x8*)((const char*)lsA[cur] + r*128 + (kb ^ ((r & 7) << 4)));
      }
#pragma unroll
      for (int fn=0; fn<4; ++fn){
        int r = wn*64 + fn*16 + (lane & 15);
        bfr[fn] = *(const bf16x8*)((const char*)lsB[cur] + r*128 + (kb ^ ((r & 7) << 4)));
      }
#pragma unroll
      for (int fm=0; fm<2; ++fm)
#pragma unroll
        for (int fn=0; fn<4; ++fn)
          acc[fm][fn] = __builtin_amdgcn_mfma_f32_16x16x32_bf16(af[fm], bfr[fn], acc[fm][fn], 0, 0, 0);
    }
    __builtin_amdgcn_s_barrier();                      // done reading cur before overwrite
  }

#pragma unroll
  for (int fm=0; fm<2; ++fm)
#pragma unroll
    for (int fn=0; fn<4; ++fn)
#pragma unroll
      for (int r=0; r<4; ++r){
        int row = m0 + wm*32 + fm*16 + ((lane >> 4) << 2) + r;
        int col = n0 + wn*64 + fn*16 + (lane & 15);
        C[(size_t)row*HH + col] = acc[fm][fn][r];
      }
}

// ---------------- chunked deferred STDP GEMM (dbuf + counted vmcnt) ---------
// Per chunk (5 steps), accumulate into f32 accumulators (in d_out):
//  w_rec acc += -100*sum_j z(t0+j+1)^T u(t0+j)  +  sum_j u(t0+j+1)^T z(t0+j)
//  w_in  acc += sum_j z^T (0.01 tp_i) + sum_j u^T (-1e-4 x)   (scales in slabs)
__global__ void __launch_bounds__(256) gemm_chunk(
    const u16* __restrict__ zRing, const u16* __restrict__ uRing,
    const u16* __restrict__ tpi01s, const u16* __restrict__ xms,
    int s0, int first, float* __restrict__ o_wrec, float* __restrict__ o_win)
{
  __shared__ u16 lsA[2][128*64];   // 16 KB each buf
  __shared__ u16 lsB[2][128*64];
  const int tid = threadIdx.x, lane = tid & 63, wid = tid >> 6;
  const int wm = wid & 1, wn = wid >> 1;
  const int xcd = blockIdx.x & 7;
  const int local = blockIdx.x >> 3;
  const bool isrec = (local < 128);

  int m0, n0, ldc; float* C;
  if (isrec){                    // w_rec: per-XCD 8x16 tile rectangle
    int tm = (xcd >> 1)*8 + (local & 7);
    int tn = (xcd & 1)*16 + (local >> 3);
    m0 = tm*128; n0 = tn*128; C = o_wrec; ldc = HH;
  } else {                       // w_in: per-XCD 8x4 tile rectangle
    int l2 = local - 128;
    int tm = (xcd >> 1)*8 + (l2 & 7);
    int tn = (xcd & 1)*4 + (l2 >> 3);
    m0 = tm*128; n0 = tn*128; C = o_win; ldc = II;
  }

  // staging invariants (lane-dependent swizzle, hoisted out of the K loop)
  int offA[4], offB[4], ldso[4];
#pragma unroll
  for (int c=0;c<4;++c){
    int q = c*4 + wid;
    int o = q*1024 + lane*16;
    int row = o >> 7;
    int cb = (o & 127) ^ ((row & 7) << 4);
    offA[c] = (m0 + row)*BB + (cb >> 1);
    offB[c] = (n0 + row)*BB + (cb >> 1);
    ldso[c] = q*1024;
  }

  auto STAGE = [&](int buf, int idx){
    int ph = (idx >= 4*TC);
    int rr = idx - (ph ? 4*TC : 0);
    int j  = rr >> 2;
    int k0 = (rr & 3) << 6;
    int sA = (s0 + j + 1) & (NSLOT-1);
    int sB = (s0 + j) & (NSLOT-1);
    const u16* __restrict__ Aslab = (ph ? uRing : zRing) + (size_t)sA*HB;
    const u16* __restrict__ Bslab = isrec
        ? ((ph ? zRing : uRing) + (size_t)sB*HB)
        : ((ph ? xms : tpi01s) + (size_t)sA*IB);
#pragma unroll
    for (int c=0;c<4;++c){
      async_cp16(Aslab + offA[c] + k0, (char*)lsA[buf] + ldso[c]);
      async_cp16(Bslab + offB[c] + k0, (char*)lsB[buf] + ldso[c]);
    }
  };

  f32x4 acc[4][4];
#pragma unroll
  for (int a=0;a<4;++a)
#pragma unroll
    for (int b=0;b<4;++b) acc[a][b] = f32x4{0.f,0.f,0.f,0.f};

  STAGE(0, 0);
#pragma unroll 1
  for (int idx = 0; idx < 8*TC; ++idx){
    int cur = idx & 1;
    if (idx < 8*TC-1){
      STAGE(cur ^ 1, idx+1);                            // 8 loads in flight
      asm volatile("s_waitcnt vmcnt(8)" ::: "memory");  // older 8 (cur buf) landed
    } else {
      asm volatile("s_waitcnt vmcnt(0)" ::: "memory");
    }
    __builtin_amdgcn_s_barrier();
    if (isrec && idx == 4*TC){        // phase switch: acc = S1 -> -100*S1
#pragma unroll
      for (int a=0;a<4;++a)
#pragma unroll
        for (int b=0;b<4;++b)
#pragma unroll
          for (int r=0;r<4;++r) acc[a][b][r] *= -100.f;
    }
#pragma unroll
    for (int kk = 0; kk < 2; ++kk){
      bf16x8 af[4], bfr[4];
      int kb = kk*64 + ((lane >> 4) << 4);
#pragma unroll
      for (int f=0; f<4; ++f){
        int ra = wm*64 + f*16 + (lane & 15);
        af[f] = *(const bf16x8*)((const char*)lsA[cur] + ra*128 + (kb ^ ((ra & 7) << 4)));
        int rb = wn*64 + f*16 + (lane & 15);
        bfr[f] = *(const bf16x8*)((const char*)lsB[cur] + rb*128 + (kb ^ ((rb & 7) << 4)));
      }
#pragma unroll
      for (int fm=0; fm<4; ++fm)
#pragma unroll
        for (int fn=0; fn<4; ++fn)
          acc[fm][fn] = __builtin_amdgcn_mfma_f32_16x16x32_bf16(af[fm], bfr[fn], acc[fm][fn], 0, 0, 0);
    }
    __builtin_amdgcn_s_barrier();     // done reading cur before next overwrite
  }

  if (first){
#pragma unroll
    for (int fm=0; fm<4; ++fm)
#pragma unroll
      for (int fn=0; fn<4; ++fn)
#pragma unroll
        for (int r=0; r<4; ++r){
          int row = m0 + wm*64 + fm*16 + ((lane >> 4) << 2) + r;
          int col = n0 + wn*64 + fn*16 + (lane & 15);
          C[(size_t)row*ldc + col] = acc[fm][fn][r];
        }
  } else {
#pragma unroll
    for (int fm=0; fm<4; ++fm)
#pragma unroll
      for (int fn=0; fn<4; ++fn)
#pragma unroll
        for (int r=0; r<4; ++r){
          int row = m0 + wm*64 + fm*16 + ((lane >> 4) << 2) + r;
          int col = n0 + wn*64 + fn*16 + (lane & 15);
          C[(size_t)row*ldc + col] += acc[fm][fn][r];
        }
  }
}

// ---------------- prep body: x cast + tp_i filter + scaled transposed slabs -
__device__ __forceinline__ void prep_body(
    const float* __restrict__ x, int t, int i0, int b0, int tid,
    u16* __restrict__ xb_buf, float* __restrict__ tpi,
    u16* __restrict__ tpi01s, u16* __restrict__ xms, int slot,
    u16 (*ls)[64*17])
{
  u16 vp[4], vx[4];
#pragma unroll
  for (int e=0;e<4;++e){
    int f = e*256 + tid;
    int il = f & 63, bl = f >> 6;
    size_t ix = ((size_t)t*BB + b0+bl)*II + i0 + il;
    size_t is = (size_t)(b0+bl)*II + i0 + il;
    float xv = x[ix];
    xb_buf[is] = f2bf(xv);
    float p = tpi[is]; p += 0.0005f*(0.001f*xv - p); tpi[is] = p;
    vp[e] = f2bf(0.01f * p);       // fold +ETA_PLUS
    vx[e] = f2bf(-1e-4f * xv);     // fold -ETA_MINUS
  }
#pragma unroll
  for (int e=0;e<4;++e){
    int f=e*256+tid; int il=f&63, bl=f>>6; int o = il*17+bl;
    ls[0][o]=vp[e]; ls[1][o]=vx[e];
  }
  __syncthreads();
#pragma unroll
  for (int e=0;e<4;++e){
    int f=e*256+tid; int bl=f&15, il=f>>4; int o=il*17+bl;
    size_t oi = (size_t)slot*IB + (size_t)(i0+il)*BB + b0 + bl;
    tpi01s[oi]=ls[0][o]; xms[oi]=ls[1][o];
  }
}

__global__ void __launch_bounds__(256) prep0(
    const float* __restrict__ x, u16* __restrict__ xb_buf,
    float* __restrict__ tpi, u16* __restrict__ tpi01s, u16* __restrict__ xms)
{
  __shared__ u16 ls[2][64*17];
  int bid = blockIdx.x;
  prep_body(x, 0, (bid & 15)*64, (bid >> 4)*16, threadIdx.x,
            xb_buf, tpi, tpi01s, xms, 1, ls);
}

// ---------------- per-step state + ring slabs + (merged) next-step prep -----
__global__ void __launch_bounds__(256) step_state(
    const float* __restrict__ pbuf,
    float* __restrict__ v, float* __restrict__ iS, float* __restrict__ sc,
    float* __restrict__ u,
    u16* __restrict__ zb, u16* __restrict__ zRing, u16* __restrict__ uRing,
    int slotZ,
    const float* __restrict__ x, int tnext, int do_prep,
    u16* __restrict__ xb_buf, float* __restrict__ tpi,
    u16* __restrict__ tpi01s, u16* __restrict__ xms, int slotP)
{
  __shared__ u16 ls[2][64*17];
  const int tid = threadIdx.x;
  const int bid = blockIdx.x;

  if (bid < 1024){
    const int h0 = (bid & 63) * 64;
    const int b0 = (bid >> 6) * 16;
    u16 vz[4], vu[4];
#pragma unroll
    for (int e=0;e<4;++e){
      int f = e*256 + tid;
      int hl = f & 63, bl = f >> 6;
      size_t idx = (size_t)(b0+bl)*HH + h0 + hl;
      float ic = pbuf[idx] + pbuf[idx + NPLANE] + pbuf[idx + 2*NPLANE]
               + pbuf[idx + 3*NPLANE] + pbuf[idx + 4*NPLANE];
      float vv = v[idx], ii = iS[idx];
      float vdec = vv + 0.05f*((0.0f - vv) + ii);
      float idec = ii - 0.1f*ii;
      float z = (vdec >= 0.5f) ? 1.0f : 0.0f;
      v[idx] = (vdec >= 0.5f) ? 0.0f : vdec;
      iS[idx] = idec + ic;
      float uu = u[idx]; uu += 0.0005f*(0.001f*z - uu); u[idx] = uu;
      sc[idx] += z;
      u16 zb16 = f2bf(z);
      zb[idx] = zb16;
      vz[e] = zb16;
      vu[e] = f2bf(uu);
    }
#pragma unroll
    for (int e=0;e<4;++e){
      int f=e*256+tid; int hl=f&63, bl=f>>6; int o = hl*17+bl;
      ls[0][o]=vz[e]; ls[1][o]=vu[e];
    }
    __syncthreads();
#pragma unroll
    for (int e=0;e<4;++e){
      int f=e*256+tid; int bl=f&15, hl=f>>4; int o=hl*17+bl;
      size_t oi = (size_t)slotZ*HB + (size_t)(h0+hl)*BB + b0 + bl;
      zRing[oi]=ls[0][o]; uRing[oi]=ls[1][o];
    }
  } else {
    if (!do_prep) return;
    int r = bid - 1024;
    prep_body(x, tnext, (r & 15)*64, (r >> 4)*16, tid,
              xb_buf, tpi, tpi01s, xms, slotP, ls);
  }
}

// ---------------- casts and finalize ----------------------------------------
__global__ void __launch_bounds__(256) cast_bf(const f32x4* __restrict__ w0,
                                               u16x4* __restrict__ wb, long long n4){
  long long i = (long long)blockIdx.x*blockDim.x + threadIdx.x;
  long long stride = (long long)gridDim.x*blockDim.x;
  for (; i < n4; i += stride){
    f32x4 vv = w0[i];
    u16x4 o;
#pragma unroll
    for (int j=0;j<4;++j) o[j] = f2bf(vv[j]);
    wb[i] = o;
  }
}

// acc = w0 + scale*acc  (o_wrec: scale=-1e-4 ; o_win: scale=1)
__global__ void __launch_bounds__(256) fin_w(const f32x4* __restrict__ w0,
                                             f32x4* __restrict__ acc,
                                             float scale, long long n4){
  long long i = (long long)blockIdx.x*blockDim.x + threadIdx.x;
  long long stride = (long long)gridDim.x*blockDim.x;
  for (; i < n4; i += stride){
    f32x4 a = acc[i], w = w0[i];
#pragma unroll
    for (int j=0;j<4;++j) a[j] = w[j] + scale*a[j];
    acc[i] = a;
  }
}

__global__ void __launch_bounds__(256) fin_logits(const float* __restrict__ sc,
                                                  float* __restrict__ logits, float* __restrict__ total){
  __shared__ float bins[LL];
  const int tid = threadIdx.x;
  const int b = blockIdx.x;
  if (tid < LL) bins[tid] = 0.f;
  __syncthreads();
#pragma unroll
  for (int e=0;e<16;++e){
    int h = e*256 + tid;
    float vv = sc[(size_t)b*HH + h];
    int a = h/409; if (a > 9) a = 9;
    atomicAdd(&bins[a], vv);
  }
  __syncthreads();
  if (tid < LL){
    float cnt = (tid==9) ? 415.f : 409.f;
    logits[b*LL + tid] = bins[tid] / (50.f * cnt);
  }
  if (tid == 0){
    float s = 0.f;
    for (int l=0;l<LL;++l) s += bins[l];
    atomicAdd(total, s);
  }
}

__global__ void __launch_bounds__(256) fin_spikecnt(const float* __restrict__ sc,
                                                    const int* __restrict__ label, float* __restrict__ out){
  int h = blockIdx.x*256 + threadIdx.x;
  int bs = blockIdx.y*32;
  float acc[LL];
#pragma unroll
  for (int j=0;j<LL;++j) acc[j] = 0.f;
  for (int b=bs; b<bs+32; ++b){
    int l = label[b];
    float vv = sc[(size_t)b*HH + h];
#pragma unroll
    for (int j=0;j<LL;++j) acc[j] += (j==l) ? vv : 0.f;
  }
#pragma unroll
  for (int j=0;j<LL;++j)
    if (acc[j] != 0.f) atomicAdd(&out[(size_t)j*HH + h], acc[j]);
}

__global__ void __launch_bounds__(256) fin_labelcnt(const int* __restrict__ label, float* __restrict__ out){
  __shared__ int bins[LL];
  const int tid = threadIdx.x;
  if (tid < LL) bins[tid] = 0;
  __syncthreads();
  atomicAdd(&bins[label[tid]], 1);
  __syncthreads();
  if (tid < LL) out[tid] = 50.f * (float)bins[tid];
}

extern "C" void kernel_launch(void* const* d_in, const int* in_sizes, int n_in,
                              void* d_out, int out_size, void* d_ws, size_t ws_size,
                              hipStream_t stream)
{
  (void)in_sizes; (void)n_in; (void)out_size; (void)ws_size;
  const float* x      = (const float*)d_in[0];
  const int*   label  = (const int*)d_in[1];
  const float* w_in0  = (const float*)d_in[2];
  const float* w_rec0 = (const float*)d_in[3];

  float* out      = (float*)d_out;
  float* o_logits = out;                            // 2560
  float* o_total  = out + 2560;                     // 1
  float* o_win    = out + 2561;                     // H*I f32 accumulator -> final
  float* o_wrec   = o_win + (size_t)HH*II;          // H*H f32 accumulator -> final
  float* o_sc     = o_wrec + (size_t)HH*HH;         // L*H
  float* o_lc     = o_sc + (size_t)LL*HH;           // L

  char* cur = (char*)d_ws;
  auto alloc = [&](size_t bytes)->char*{ char* p = cur; cur += (bytes + 255) & ~(size_t)255; return p; };
  u16*   wib    = (u16*)  alloc((size_t)HH*II*2);        //  8.4 MB
  u16*   wrb    = (u16*)  alloc((size_t)HH*HH*2);        // 33.6 MB
  float* v      = (float*)alloc(NPLANE*4);               //  4.2
  float* iS     = (float*)alloc(NPLANE*4);               //  4.2
  float* sc     = (float*)alloc(NPLANE*4);               //  4.2
  float* u      = (float*)alloc(NPLANE*4);               //  4.2
  float* pbuf   = (float*)alloc(5*NPLANE*4);             // 21.0
  u16*   zb     = (u16*)  alloc(NPLANE*2);               //  2.1
  u16*   xb_buf = (u16*)  alloc((size_t)BB*II*2);        //  0.5
  float* tpi    = (float*)alloc((size_t)BB*II*4);        //  1.0
  u16*   zRing  = (u16*)  alloc((size_t)NSLOT*HB*2);     // 16.8
  u16*   uRing  = (u16*)  alloc((size_t)NSLOT*HB*2);     // 16.8
  u16*   tpi01s = (u16*)  alloc((size_t)NSLOT*IB*2);     //  4.2
  u16*   xms    = (u16*)  alloc((size_t)NSLOT*IB*2);     //  4.2
                                                         // total ~123 MB

  hipMemsetAsync(v,     0, NPLANE*4, stream);
  hipMemsetAsync(iS,    0, NPLANE*4, stream);
  hipMemsetAsync(sc,    0, NPLANE*4, stream);
  hipMemsetAsync(u,     0, NPLANE*4, stream);
  hipMemsetAsync(zb,    0, NPLANE*2, stream);
  hipMemsetAsync(tpi,   0, (size_t)BB*II*4, stream);
  hipMemsetAsync(zRing, 0, HB*2, stream);                // slot 0 = z(0) = 0
  hipMemsetAsync(uRing, 0, HB*2, stream);                // slot 0 = u(0) = 0
  hipMemsetAsync(o_total, 0, 4, stream);
  hipMemsetAsync(o_sc,  0, (size_t)LL*HH*4, stream);

  cast_bf<<<1024, 256, 0, stream>>>((const f32x4*)w_in0,  (u16x4*)wib, (long long)HH*II/4);
  cast_bf<<<2048, 256, 0, stream>>>((const f32x4*)w_rec0, (u16x4*)wrb, (long long)HH*HH/4);
  prep0<<<256, 256, 0, stream>>>(x, xb_buf, tpi, tpi01s, xms);

  for (int t = 0; t < TSTEPS; ++t){
    gemm_fwd<<<640, 256, 0, stream>>>(xb_buf, wib, zb, wrb, pbuf);

    step_state<<<1280, 256, 0, stream>>>(
        pbuf, v, iS, sc, u, zb, zRing, uRing, (t+1) & (NSLOT-1),
        x, t+1, (t < TSTEPS-1) ? 1 : 0,
        xb_buf, tpi, tpi01s, xms, (t+2) & (NSLOT-1));

    if ((t+1) % TC == 0){
      int s0 = (t+1-TC) & (NSLOT-1);
      gemm_chunk<<<1280, 256, 0, stream>>>(zRing, uRing, tpi01s, xms,
                                           s0, (t+1 == TC) ? 1 : 0,
                                           o_wrec, o_win);
    }
  }

  fin_w<<<2048, 256, 0, stream>>>((const f32x4*)w_rec0, (f32x4*)o_wrec, -1e-4f, (long long)HH*HH/4);
  fin_w<<<1024, 256, 0, stream>>>((const f32x4*)w_in0,  (f32x4*)o_win,  1.0f,   (long long)HH*II/4);

  fin_logits  <<<BB, 256, 0, stream>>>(sc, o_logits, o_total);
  fin_spikecnt<<<dim3(HH/256, 8), 256, 0, stream>>>(sc, label, o_sc);
  fin_labelcnt<<<1, 256, 0, stream>>>(label, o_lc);
}